// Round 4
// baseline (735.114 us; speedup 1.0000x reference)
//
#include <hip/hip_runtime.h>
#include <hip/hip_bf16.h>

typedef __bf16 bf16;
typedef __bf16 bf16x8 __attribute__((ext_vector_type(8)));
typedef float f32x4 __attribute__((ext_vector_type(4)));
typedef float f32x8 __attribute__((ext_vector_type(8)));

#define NB   32768
#define EMB  768
#define MSUB 32
#define KC   256
#define DSUB 24

// ws layout (bytes):
//   [0,     768K )  cb_t  : fp32 [32][24][256]  (d-major, k contiguous)
//   [1M,  2.125M)  rot_bf: bf16 [768][768]
//   [4M,   100M )  xr    : fp32 [32768][768]    (natural layout)

__device__ __forceinline__ bf16x8 cvt8(float4 a, float4 b) {
    bf16x8 r;
    r[0] = (bf16)a.x; r[1] = (bf16)a.y; r[2] = (bf16)a.z; r[3] = (bf16)a.w;
    r[4] = (bf16)b.x; r[5] = (bf16)b.y; r[6] = (bf16)b.z; r[7] = (bf16)b.w;
    return r;
}

// ---------------------------------------------------------------- kernel 0
__global__ __launch_bounds__(256, 4)
void pq_prep(const float* __restrict__ cb, const float* __restrict__ rot,
             float* __restrict__ cb_t, bf16* __restrict__ rot_bf) {
    const int b = blockIdx.x;
    const int t = threadIdx.x;
    if (b < 288) {                       // rot: 768*768 = 288*2048
        const int o = b * 2048 + t * 8;
        float4 a0 = *(const float4*)(rot + o);
        float4 a1 = *(const float4*)(rot + o + 4);
        *(bf16x8*)(rot_bf + o) = cvt8(a0, a1);
    } else {                             // cb transpose: [m][k][d] -> [m][d][k]
        const int m = b - 288;           // 0..31, t = k
        const float* src = cb + (size_t)(m * KC + t) * DSUB;
        float v[24];
        #pragma unroll
        for (int i = 0; i < 6; ++i)
            *(float4*)(v + 4 * i) = *(const float4*)(src + 4 * i);
        #pragma unroll
        for (int d = 0; d < DSUB; ++d)
            cb_t[((size_t)m * DSUB + d) * KC + t] = v[d];
    }
}

// ---------------------------------------------------------------- kernel 1
// xr = x @ rot^T via swapped MFMA: D[j][row] = mfma(A=rot_frag, B=x_frag).
// Acc regs then hold 4 CONSECUTIVE j per lane -> direct f32x4 stores.
__global__ __launch_bounds__(512, 3)
void pq_rot(const float* __restrict__ x, const bf16* __restrict__ rot_bf,
            float* __restrict__ xr) {
    __shared__ bf16 g_lds[96 * 32 * 8];   // x bf16 granules [e8][row][slot], 48 KiB

    const int tid  = threadIdx.x;
    const int w    = tid >> 6;
    const int lane = tid & 63;
    const int l15  = lane & 15;
    const int lg   = lane >> 4;
    const int rowbase = blockIdx.x * 32;

    // stage x -> bf16 granules (each element read from HBM exactly once)
    #pragma unroll
    for (int i = 0; i < 6; ++i) {
        const int oct = i * 512 + tid;
        const int row = oct & 31;
        const int e8  = oct >> 5;
        const float* xp = x + (size_t)(rowbase + row) * EMB + e8 * 8;
        *(bf16x8*)&g_lds[(e8 * 32 + row) * 8] =
            cvt8(*(const float4*)xp, *(const float4*)(xp + 4));
    }
    __syncthreads();

    f32x4 acc[2][6];
    #pragma unroll
    for (int rt = 0; rt < 2; ++rt)
        #pragma unroll
        for (int jt = 0; jt < 6; ++jt)
            acc[rt][jt] = (f32x4){0.f, 0.f, 0.f, 0.f};

    const int jbase = w * 96;
    #pragma unroll 2
    for (int e0 = 0; e0 < EMB; e0 += 32) {
        bf16x8 xfrag[2];
        #pragma unroll
        for (int rt = 0; rt < 2; ++rt)
            xfrag[rt] = *(const bf16x8*)&g_lds[(((e0 >> 3) + lg) * 32 + rt * 16 + l15) * 8];
        #pragma unroll
        for (int jt = 0; jt < 6; ++jt) {
            const bf16* bp = rot_bf + (size_t)(jbase + jt * 16 + l15) * EMB + e0 + lg * 8;
            bf16x8 rotfrag = *(const bf16x8*)bp;
            // swapped operands: first dim = j, second dim = row
            acc[0][jt] = __builtin_amdgcn_mfma_f32_16x16x32_bf16(rotfrag, xfrag[0], acc[0][jt], 0, 0, 0);
            acc[1][jt] = __builtin_amdgcn_mfma_f32_16x16x32_bf16(rotfrag, xfrag[1], acc[1][jt], 0, 0, 0);
        }
    }

    // epilogue: acc[rt][jt] regs r = xr[rowbase+rt*16+l15][jbase+jt*16+lg*4+r]
    #pragma unroll
    for (int rt = 0; rt < 2; ++rt) {
        #pragma unroll
        for (int jt = 0; jt < 6; ++jt) {
            float* p = xr + (size_t)(rowbase + rt * 16 + l15) * EMB
                          + jbase + jt * 16 + lg * 4;
            *(f32x4*)p = acc[rt][jt];
        }
    }
}

// ---------------------------------------------------------------- kernel 2
// scores via pure VALU: lane owns k = 4*lane..4*lane+3; stores are 1 KiB
// contiguous per instruction. xs is wave-uniform (SMEM s_load, SGPR FMA src).
__global__ __launch_bounds__(512, 4)
void pq_scores(const float* __restrict__ xr, const float* __restrict__ cb_t,
               float* __restrict__ out) {
    const int tid  = threadIdx.x;
    const int lane = tid & 63;
    const int w    = tid >> 6;
    const int rowbase = blockIdx.x * 32;

    #pragma unroll 1
    for (int mm = 0; mm < 4; ++mm) {
        const int m = __builtin_amdgcn_readfirstlane((w << 2) + mm);

        // codebook chunk for this m: cbv[d][kk], k = 4*lane+kk (96 VGPRs)
        f32x4 cbv[24];
        const float* cbp = cb_t + (size_t)m * (DSUB * KC) + 4 * lane;
        #pragma unroll
        for (int d = 0; d < DSUB; ++d)
            cbv[d] = *(const f32x4*)(cbp + d * KC);

        const float* xrow = xr + (size_t)rowbase * EMB + m * DSUB;
        float* outm = out + ((size_t)rowbase * MSUB + m) * KC + 4 * lane;

        f32x8 xA0, xA1, xA2, xB0, xB1, xB2;
        auto loadx = [&](int r, f32x8& x0, f32x8& x1, f32x8& x2) {
            const float* p = xrow + (size_t)r * EMB;
            x0 = *(const f32x8*)(p);
            x1 = *(const f32x8*)(p + 8);
            x2 = *(const f32x8*)(p + 16);
        };
        auto comp = [&](int r, const f32x8& x0, const f32x8& x1, const f32x8& x2) {
            f32x4 acc = (f32x4){0.f, 0.f, 0.f, 0.f};
            #pragma unroll
            for (int d = 0; d < 8; ++d) acc += cbv[d]      * x0[d];
            #pragma unroll
            for (int d = 0; d < 8; ++d) acc += cbv[d + 8]  * x1[d];
            #pragma unroll
            for (int d = 0; d < 8; ++d) acc += cbv[d + 16] * x2[d];
            *(f32x4*)(outm + (size_t)r * (MSUB * KC)) = acc;
        };

        loadx(0, xA0, xA1, xA2);
        loadx(1, xB0, xB1, xB2);
        #pragma unroll 1
        for (int r = 0; r < 32; r += 2) {
            comp(r, xA0, xA1, xA2);
            if (r + 2 < 32) loadx(r + 2, xA0, xA1, xA2);
            comp(r + 1, xB0, xB1, xB2);
            if (r + 3 < 32) loadx(r + 3, xB0, xB1, xB2);
        }
    }
}

extern "C" void kernel_launch(void* const* d_in, const int* in_sizes, int n_in,
                              void* d_out, int out_size, void* d_ws, size_t ws_size,
                              hipStream_t stream) {
    const float* x   = (const float*)d_in[0];   // [32768, 768]
    const float* cbk = (const float*)d_in[1];   // [32, 256, 24]
    const float* rot = (const float*)d_in[2];   // [768, 768]
    float* out = (float*)d_out;                 // [32768, 32, 256]

    char* ws = (char*)d_ws;
    float* cb_t   = (float*)(ws);
    bf16*  rot_bf = (bf16*)(ws + (1u << 20));
    float* xr     = (float*)(ws + (4u << 20));

    hipLaunchKernelGGL(pq_prep,   dim3(320),  dim3(256), 0, stream, cbk, rot, cb_t, rot_bf);
    hipLaunchKernelGGL(pq_rot,    dim3(1024), dim3(512), 0, stream, x, rot_bf, xr);
    hipLaunchKernelGGL(pq_scores, dim3(1024), dim3(512), 0, stream, xr, cb_t, out);
}